// Round 7
// baseline (3156.104 us; speedup 1.0000x reference)
//
#include <hip/hip_runtime.h>
#include <stdint.h>

typedef unsigned short u16;
typedef __attribute__((ext_vector_type(8))) short bf16x8;
typedef __attribute__((ext_vector_type(4))) float f32x4;

#define EE 512
#define NH 8
#define HDm 64
#define SS 128
#define NB 8
#define NL 4
#define QKVW 1536

__device__ __forceinline__ float bf2f(u16 v){ union{uint32_t u; float f;} c; c.u=((uint32_t)v)<<16; return c.f; }
__device__ __forceinline__ u16 f2bf(float f){ union{float f; uint32_t u;} c; c.f=f; uint32_t u=c.u; return (u16)((u + 0x7FFFu + ((u>>16)&1u))>>16); }

__device__ __forceinline__ f32x4 mfma16(bf16x8 a, bf16x8 b, f32x4 c){
  return __builtin_amdgcn_mfma_f32_16x16x32_bf16(a,b,c,0,0,0);
}

__device__ __forceinline__ void gload16(const u16* g, u16* l){
  auto gp = reinterpret_cast<const __attribute__((address_space(1))) uint32_t*>(reinterpret_cast<uintptr_t>(g));
  auto lp = reinterpret_cast<__attribute__((address_space(3))) uint32_t*>(reinterpret_cast<uintptr_t>(l));
  __builtin_amdgcn_global_load_lds(gp, lp, 16, 0, 0);
}

#define ABAR() asm volatile("s_barrier" ::: "memory")
#define SB0()  __builtin_amdgcn_sched_barrier(0)
#define PRIO1() __builtin_amdgcn_s_setprio(1)
#define PRIO0() __builtin_amdgcn_s_setprio(0)

// run groups of 16 positions (U units per 128-row tile)
__device__ __forceinline__ void run_map(int bid, int cb, int U, int& r, int& u){
  int rr = 0;
  for (;;){
    int g = (cb + rr) >> 4;
    int gend = ((g + 1) << 4) - cb;
    int upr = (g + 1) * U;
    int span = (gend - rr) * upr;
    if (bid < span){ r = rr + bid / upr; u = bid % upr; return; }
    bid -= span; rr = gend;
  }
}
// run groups of 32 positions (256-row tiles)
__device__ __forceinline__ void run_map256(int bid, int cb, int& r, int& u){
  int rr = 0;
  for (;;){
    int g = (cb + rr) >> 5;
    int gend = ((g + 1) << 5) - cb;
    int upr = g + 1;
    int span = (gend - rr) * upr;
    if (bid < span){ r = rr + bid / upr; u = bid % upr; return; }
    bid -= span; rr = gend;
  }
}

// coalesced transpose: dst[l*dstL + (dstOff + o)*512 + i] = bf16(W[l][i][o])
__global__ __launch_bounds__(256) void wtransT(const float* __restrict__ W, u16* __restrict__ dst,
                                               int dstL, int dstOff){
  __shared__ float tl[32][33];
  int l = blockIdx.y;
  int tile = blockIdx.x;
  int ot = tile & 15, it = tile >> 4;
  int t = threadIdx.x;
  int c = t & 31, r = t >> 5;
  #pragma unroll
  for (int k=0;k<4;k++){
    int ri = it*32 + r + k*8;
    tl[c][r + k*8] = W[(size_t)l*262144 + (size_t)ri*512 + ot*32 + c];
  }
  __syncthreads();
  #pragma unroll
  for (int k=0;k<4;k++){
    int ro = ot*32 + r + k*8;
    dst[(size_t)l*dstL + (size_t)(dstOff + ro)*512 + it*32 + c] = f2bf(tl[r + k*8][c]);
  }
}

__global__ __launch_bounds__(256) void bfuse(const float* __restrict__ bq, const float* __restrict__ bk,
                                             const float* __restrict__ bv, float* __restrict__ bqkv){
  int i = blockIdx.x*256 + threadIdx.x;         // L*1536
  int l = i / QKVW, n = i % QKVW;
  const float* b = (n < 512) ? bq : ((n < 1024) ? bk : bv);
  bqkv[i] = b[l*EE + (n & 511)];
}

// h0[p][b][e] = bf16(x[b][p][e])
__global__ __launch_bounds__(256) void hinit(const float* __restrict__ x, u16* __restrict__ h0){
  int i = (blockIdx.x*256 + threadIdx.x)*8;
  int e = i & 511;
  int pb = i >> 9;
  int b = pb & 7, pp = pb >> 3;
  const float* xp = x + (((size_t)b*SS + pp)<<9) + e;
  union{ bf16x8 v; u16 u[8]; } r;
  #pragma unroll
  for (int j=0;j<8;j++) r.u[j] = f2bf(xp[j]);
  *(bf16x8*)(h0 + i) = r.v;
}

// ===== 256x256 8-phase GEMM (QKV only), proven in R3/R6: 1.58 PF at scale =====
__global__ __launch_bounds__(512, 2) void gemm256(const u16* __restrict__ A, const u16* __restrict__ Bt,
                                                  const float* __restrict__ bias,
                                                  u16* __restrict__ o0, u16* __restrict__ o1, u16* __restrict__ o2,
                                                  int cb){
  extern __shared__ u16 lds[];   // 4 slots * 16384 u16 = 128 KB
  int t = threadIdx.x;
  size_t m0;
  if (cb < 0){
    m0 = (size_t)blockIdx.x * 256;
  } else {
    int r, tile; run_map256(blockIdx.x, cb, r, tile);
    m0 = (size_t)r*1024 + (size_t)tile*256;
  }
  int n0 = blockIdx.y * 256;
  int wid = t>>6, lane = t&63;
  int wm = wid>>2, wn = wid&3;
  int lr = lane&15, lq = lane>>4;

  auto stage = [&](int kt, int h){
    int slot = (2*kt + h) & 3;
    u16* sb = lds + slot*16384;
    int k0 = kt*64;
    #pragma unroll
    for (int j=0;j<2;j++){
      int ch = j*512 + t;
      int row = ch>>3, cg = (ch&7) ^ (row&7);
      gload16(A  + (m0 + (size_t)(h*128 + row))*EE + k0 + cg*8, sb + ch*8);
      gload16(Bt + (size_t)(n0 + h*128 + row)*EE   + k0 + cg*8, sb + 8192 + ch*8);
    }
  };
  auto rdA = [&](int kt, int mi, int kk)->bf16x8{
    int slot = (2*kt + wm) & 3;
    int row = mi*16 + lr;
    int c = (kk*4 + lq) ^ (row&7);
    return *(const bf16x8*)(lds + slot*16384 + row*64 + c*8);
  };
  auto rdB = [&](int kt, int ni, int kk)->bf16x8{
    int slot = (2*kt + (wn>>1)) & 3;
    int row = (wn&1)*64 + ni*16 + lr;
    int c = (kk*4 + lq) ^ (row&7);
    return *(const bf16x8*)(lds + slot*16384 + 8192 + row*64 + c*8);
  };

  f32x4 acc[8][4] = {};
  stage(0,0); stage(0,1); stage(1,0); stage(1,1);

  #pragma unroll
  for (int kt=0; kt<8; kt++){
    if (kt < 7) asm volatile("s_waitcnt vmcnt(8)" ::: "memory");
    else        asm volatile("s_waitcnt vmcnt(0)" ::: "memory");
    ABAR();
    bf16x8 b0[4][2], a[4][2];
    #pragma unroll
    for (int ni=0;ni<4;ni++){ b0[ni][0]=rdB(kt,ni,0); b0[ni][1]=rdB(kt,ni,1); }
    #pragma unroll
    for (int mi=0;mi<4;mi++){ a[mi][0]=rdA(kt,mi,0); a[mi][1]=rdA(kt,mi,1); }
    PRIO1();
    #pragma unroll
    for (int mi=0;mi<4;mi++)
      #pragma unroll
      for (int ni=0;ni<2;ni++)
        #pragma unroll
        for (int kk=0;kk<2;kk++)
          acc[mi][ni] = mfma16(a[mi][kk], b0[ni][kk], acc[mi][ni]);
    PRIO0(); SB0(); ABAR();
    PRIO1();
    #pragma unroll
    for (int mi=0;mi<4;mi++)
      #pragma unroll
      for (int ni=2;ni<4;ni++)
        #pragma unroll
        for (int kk=0;kk<2;kk++)
          acc[mi][ni] = mfma16(a[mi][kk], b0[ni][kk], acc[mi][ni]);
    PRIO0(); SB0(); ABAR();
    #pragma unroll
    for (int mi=0;mi<4;mi++){ a[mi][0]=rdA(kt,mi+4,0); a[mi][1]=rdA(kt,mi+4,1); }
    PRIO1();
    #pragma unroll
    for (int mi=0;mi<4;mi++)
      #pragma unroll
      for (int ni=0;ni<2;ni++)
        #pragma unroll
        for (int kk=0;kk<2;kk++)
          acc[mi+4][ni] = mfma16(a[mi][kk], b0[ni][kk], acc[mi+4][ni]);
    PRIO0(); SB0(); ABAR();
    if (kt < 6){ stage(kt+2,0); stage(kt+2,1); }
    PRIO1();
    #pragma unroll
    for (int mi=0;mi<4;mi++)
      #pragma unroll
      for (int ni=2;ni<4;ni++)
        #pragma unroll
        for (int kk=0;kk<2;kk++)
          acc[mi+4][ni] = mfma16(a[mi][kk], b0[ni][kk], acc[mi+4][ni]);
    PRIO0(); SB0(); ABAR();
  }

  int sel = n0 >> 9;
  u16* outp = sel==0 ? o0 : (sel==1 ? o1 : o2);
  int nb = n0 & 511;
  #pragma unroll
  for (int ni=0;ni<4;ni++){
    int coln = wn*64 + ni*16 + lr;
    float bv = bias[n0 + coln];
    int col = nb + coln;
    #pragma unroll
    for (int mi=0;mi<8;mi++){
      #pragma unroll
      for (int j=0;j<4;j++){
        size_t row = m0 + (size_t)(wm*128 + mi*16 + lq*4 + j);
        outp[row*EE + col] = f2bf(acc[mi][ni][j] + bv);
      }
    }
  }
}

// ===== fused GEMM + residual(+relu) + LayerNorm (+optional output extract) =====
// BM=128, BN=512 (full row per block), BK=32, 8 waves (2m x 4n), wave tile 64x128.
// 2-slot dbuf (80KB), counted vmcnt(5). MODE 1: Wo (+bias+res); 2: FF (relu(+bias)+res).
template<int MODE>
__global__ __launch_bounds__(512) void gemm_ln(const u16* __restrict__ A, const u16* __restrict__ Bt,
                                               const float* __restrict__ bias, const u16* __restrict__ res,
                                               size_t res_mask, const float* __restrict__ lng,
                                               const float* __restrict__ lnb, u16* __restrict__ outh,
                                               float* __restrict__ fout, int last, int cb){
  extern __shared__ u16 lds[];   // 2 slots * 20480 u16 = 80 KB ; epilogue overlays float2 red[512]
  int t = threadIdx.x;
  int r, tile; run_map(blockIdx.x, cb, 1, r, tile);
  int m_run = cb + r;
  size_t m0 = (size_t)r*1024 + (size_t)tile*128;
  int wid=t>>6, lane=t&63;
  int wm=wid>>2, wn=wid&3, lr=lane&15, lq=lane>>4;

  auto stage = [&](int kt, int slot){
    u16* sb = lds + slot*20480;
    int k0 = kt*32;
    #pragma unroll
    for (int j=0;j<5;j++){
      int ch = j*512 + t;
      int row = ch>>2, c = ch&3;
      const u16* src;
      if (j == 0) src = A  + (m0 + (size_t)row)*EE + k0 + c*8;          // rows 0..127 -> A
      else        src = Bt + ((size_t)(row-128))*EE + k0 + c*8;         // rows 128..639 -> B
      gload16(src, sb + ch*8);
    }
  };

  f32x4 acc[4][8] = {};
  stage(0,0); stage(1,1);

  #pragma unroll
  for (int kt=0; kt<16; kt++){
    int slot = kt & 1;
    if (kt < 15) asm volatile("s_waitcnt vmcnt(5)" ::: "memory");
    else         asm volatile("s_waitcnt vmcnt(0)" ::: "memory");
    ABAR();
    bf16x8 a[4], b[8];
    #pragma unroll
    for (int mi=0;mi<4;mi++){
      int row = wm*64 + mi*16 + lr;
      a[mi] = *(const bf16x8*)(lds + slot*20480 + row*32 + lq*8);
    }
    #pragma unroll
    for (int ni=0;ni<8;ni++){
      int brow = wn*128 + ni*16 + lr;
      b[ni] = *(const bf16x8*)(lds + slot*20480 + 4096 + brow*32 + lq*8);
    }
    asm volatile("s_waitcnt lgkmcnt(0)" ::: "memory");
    SB0();
    ABAR();
    if (kt < 14) stage(kt+2, slot);
    PRIO1();
    #pragma unroll
    for (int mi=0;mi<4;mi++)
      #pragma unroll
      for (int ni=0;ni<8;ni++)
        acc[mi][ni] = mfma16(a[mi], b[ni], acc[mi][ni]);
    PRIO0();
  }

  // ---- epilogue: bias (+relu) + residual, then per-row LayerNorm in f32 ----
  f32x4 psum[4] = {{0,0,0,0},{0,0,0,0},{0,0,0,0},{0,0,0,0}};
  f32x4 psq[4]  = {{0,0,0,0},{0,0,0,0},{0,0,0,0},{0,0,0,0}};
  #pragma unroll
  for (int ni=0;ni<8;ni++){
    int col = wn*128 + ni*16 + lr;
    float bb = bias[col];
    #pragma unroll
    for (int mi=0;mi<4;mi++){
      #pragma unroll
      for (int j=0;j<4;j++){
        size_t row = m0 + (size_t)(wm*64 + mi*16 + lq*4 + j);
        float v = acc[mi][ni][j] + bb;
        if (MODE==2) v = fmaxf(v, 0.f);
        v += bf2f(res[(row & res_mask)*EE + col]);
        acc[mi][ni][j] = v;
        psum[mi][j] += v; psq[mi][j] += v*v;
      }
    }
  }
  // reduce across the 16 lr-lanes (same row)
  #pragma unroll
  for (int o=1;o<16;o<<=1){
    #pragma unroll
    for (int mi=0;mi<4;mi++)
      #pragma unroll
      for (int j=0;j<4;j++){
        psum[mi][j] += __shfl_xor(psum[mi][j], o);
        psq[mi][j]  += __shfl_xor(psq[mi][j], o);
      }
  }
  float2* red = (float2*)lds;        // 128 rows x 4 waves
  __syncthreads();
  if (lr == 0){
    #pragma unroll
    for (int mi=0;mi<4;mi++)
      #pragma unroll
      for (int j=0;j<4;j++)
        red[(wm*64 + mi*16 + lq*4 + j)*4 + wn] = make_float2(psum[mi][j], psq[mi][j]);
  }
  __syncthreads();
  float mean_[4][4], rstd_[4][4];
  #pragma unroll
  for (int mi=0;mi<4;mi++){
    #pragma unroll
    for (int j=0;j<4;j++){
      int row128 = wm*64 + mi*16 + lq*4 + j;
      float2 s0 = red[row128*4+0], s1 = red[row128*4+1], s2 = red[row128*4+2], s3 = red[row128*4+3];
      float sm = s0.x + s1.x + s2.x + s3.x;
      float sq = s0.y + s1.y + s2.y + s3.y;
      float mu = sm * (1.f/512.f);
      float var = sq * (1.f/512.f) - mu*mu;
      mean_[mi][j] = mu;
      rstd_[mi][j] = rsqrtf(var + 1e-5f);
    }
  }
  #pragma unroll
  for (int ni=0;ni<8;ni++){
    int col = wn*128 + ni*16 + lr;
    float gg = lng[col], bb2 = lnb[col];
    #pragma unroll
    for (int mi=0;mi<4;mi++){
      #pragma unroll
      for (int j=0;j<4;j++){
        float vv = (acc[mi][ni][j] - mean_[mi][j]) * rstd_[mi][j] * gg + bb2;
        u16 hb = f2bf(vv);
        size_t row = m0 + (size_t)(wm*64 + mi*16 + lq*4 + j);
        outh[row*EE + col] = hb;
        if (last){
          int row16 = tile*128 + wm*64 + mi*16 + lq*4 + j;
          int p = row16 >> 3, b3 = row16 & 7;
          if (p == m_run) fout[((size_t)b3*SS + p)*EE + col] = bf2f(hb);
        }
      }
    }
  }
}

// one block per (run, batch, head); 512-wide planes; O written into q plane
__global__ __launch_bounds__(256) void attn(const u16* __restrict__ Q, const u16* __restrict__ K,
                                            const u16* __restrict__ V, u16* __restrict__ Oq,
                                            int cb, int shared_qkv){
  __shared__ u16 Ks[128*72];
  __shared__ u16 Vt[64*136];
  __shared__ u16 Ps[4][16*136];
  int t = threadIdx.x;
  int idx = blockIdx.x;
  int hh = idx & 7, b = (idx>>3)&7, r = idx>>6;
  int m_run = cb + r;
  const size_t RS = (size_t)SS*NB*EE;
  size_t rbase = shared_qkv ? 0 : (size_t)r*RS;
  size_t hb = (size_t)b*EE + hh*HDm;
  size_t obase = (size_t)r*RS + hb;
  int nkc = m_run/32 + 1;
  int nkt = nkc*2;
  int nqt = m_run/16 + 1;
  int nkr = nkt*16;
  for (int i=t; i<nkr*8; i+=256){
    int row=i>>3, c=(i&7)*8;
    *(uint4*)(Ks + row*72 + c) = *(const uint4*)(K + rbase + (size_t)row*NB*EE + hb + c);
  }
  for (int i=t; i<nkr*8; i+=256){
    int row=i>>3, c=(i&7)*8;
    uint4 raw = *(const uint4*)(V + rbase + (size_t)row*NB*EE + hb + c);
    const u16* pv = (const u16*)&raw;
    #pragma unroll
    for (int j=0;j<8;j++) Vt[(c+j)*136 + row] = pv[j];
  }
  __syncthreads();
  int wid=t>>6, lane=t&63, lr=lane&15, g=lane>>4, lk=(lane>>4)*8;
  u16* Pw = Ps[wid];
  for (int iq=0; iq<2; iq++){
    int qt = wid*2 + iq;
    if (qt >= nqt) continue;
    const u16* qrow = Q + rbase + (size_t)(qt*16+lr)*NB*EE + hb;
    bf16x8 qa0 = *(const bf16x8*)(qrow + lk);
    bf16x8 qa1 = *(const bf16x8*)(qrow + 32 + lk);
    f32x4 sc[8];
    #pragma unroll
    for (int kt=0;kt<8;kt++){
      if (kt < nkt){
        f32x4 c = {};
        bf16x8 kb0 = *(const bf16x8*)(Ks + (kt*16+lr)*72 + lk);
        bf16x8 kb1 = *(const bf16x8*)(Ks + (kt*16+lr)*72 + 32 + lk);
        c = mfma16(qa0, kb0, c);
        c = mfma16(qa1, kb1, c);
        int key = kt*16 + lr;
        #pragma unroll
        for (int i2=0;i2<4;i2++)
          sc[kt][i2] = (key <= m_run) ? c[i2]*0.125f : -1e9f;
      }
    }
    #pragma unroll
    for (int i2=0;i2<4;i2++){
      float v = -3.0e38f;
      #pragma unroll
      for (int kt=0;kt<8;kt++) if (kt<nkt) v = fmaxf(v, sc[kt][i2]);
      v = fmaxf(v, __shfl_xor(v,1));
      v = fmaxf(v, __shfl_xor(v,2));
      v = fmaxf(v, __shfl_xor(v,4));
      v = fmaxf(v, __shfl_xor(v,8));
      float s = 0.f;
      #pragma unroll
      for (int kt=0;kt<8;kt++) if (kt<nkt){ float e2=__expf(sc[kt][i2]-v); sc[kt][i2]=e2; s+=e2; }
      s += __shfl_xor(s,1); s += __shfl_xor(s,2); s += __shfl_xor(s,4); s += __shfl_xor(s,8);
      float inv = 1.f/s;
      #pragma unroll
      for (int kt=0;kt<8;kt++) if (kt<nkt) sc[kt][i2] *= inv;
    }
    #pragma unroll
    for (int kt=0;kt<8;kt++) if (kt<nkt){
      #pragma unroll
      for (int i2=0;i2<4;i2++)
        Pw[(g*4+i2)*136 + kt*16 + lr] = f2bf(sc[kt][i2]);
    }
    f32x4 oa[4] = {};
    #pragma unroll
    for (int kc=0;kc<4;kc++) if (kc<nkc){
      bf16x8 pa = *(const bf16x8*)(Pw + lr*136 + kc*32 + lk);
      #pragma unroll
      for (int dt=0;dt<4;dt++){
        bf16x8 vb = *(const bf16x8*)(Vt + (dt*16+lr)*136 + kc*32 + lk);
        oa[dt] = mfma16(pa, vb, oa[dt]);
      }
    }
    #pragma unroll
    for (int dt=0;dt<4;dt++){
      #pragma unroll
      for (int j=0;j<4;j++){
        size_t prow = (size_t)(qt*16 + g*4 + j);
        Oq[obase + prow*NB*EE + dt*16 + lr] = f2bf(oa[dt][j]);
      }
    }
  }
}

extern "C" void kernel_launch(void* const* d_in, const int* in_sizes, int n_in,
                              void* d_out, int out_size, void* d_ws, size_t ws_size,
                              hipStream_t stream){
  const float* x   = (const float*)d_in[0];
  const float* Wq  = (const float*)d_in[1];
  const float* bq  = (const float*)d_in[2];
  const float* Wk  = (const float*)d_in[3];
  const float* bk  = (const float*)d_in[4];
  const float* Wv  = (const float*)d_in[5];
  const float* bv  = (const float*)d_in[6];
  const float* Wo  = (const float*)d_in[7];
  const float* bo  = (const float*)d_in[8];
  const float* Wf  = (const float*)d_in[9];
  const float* bfb = (const float*)d_in[10];
  const float* g1  = (const float*)d_in[11];
  const float* b1  = (const float*)d_in[12];
  const float* g2  = (const float*)d_in[13];
  const float* b2  = (const float*)d_in[14];
  float* out = (float*)d_out;

  hipFuncSetAttribute((const void*)gemm256,    hipFuncAttributeMaxDynamicSharedMemorySize, 131072);
  hipFuncSetAttribute((const void*)gemm_ln<1>, hipFuncAttributeMaxDynamicSharedMemorySize, 81920);
  hipFuncSetAttribute((const void*)gemm_ln<2>, hipFuncAttributeMaxDynamicSharedMemorySize, 81920);

  uint8_t* p = (uint8_t*)d_ws;
  u16* WqkvT = (u16*)p; p += (size_t)NL*QKVW*EE*2;   // 6 MB
  u16* WoT   = (u16*)p; p += (size_t)NL*EE*EE*2;     // 2 MB
  u16* WfT   = (u16*)p; p += (size_t)NL*EE*EE*2;     // 2 MB
  float* bqkv= (float*)p; p += (size_t)NL*QKVW*4;    // 24 KB
  u16* h0    = (u16*)p; p += (size_t)SS*NB*EE*2;     // 1 MB
  u16* q0    = (u16*)p; p += (size_t)SS*NB*EE*2;
  u16* k0    = (u16*)p; p += (size_t)SS*NB*EE*2;
  u16* v0    = (u16*)p; p += (size_t)SS*NB*EE*2;
  size_t used = (size_t)(p - (uint8_t*)d_ws);

  int RC = 128;
  const size_t PER_RUN = (size_t)SS*NB*EE*2*4;       // h,q,k,v = 4 MiB/run
  while (RC > 1 && used + (size_t)RC*PER_RUN > ws_size) RC >>= 1;

  const size_t BUF = (size_t)RC*SS*NB*EE*2;
  u16* h   = (u16*)p; p += BUF;
  u16* q   = (u16*)p; p += BUF;
  u16* k   = (u16*)p; p += BUF;
  u16* v   = (u16*)p; p += BUF;

  const size_t NOMASK = ~(size_t)0;
  const int QL = QKVW*EE;
  const int OL = EE*EE;

  wtransT<<<dim3(256,NL),256,0,stream>>>(Wq, WqkvT, QL, 0);
  wtransT<<<dim3(256,NL),256,0,stream>>>(Wk, WqkvT, QL, 512);
  wtransT<<<dim3(256,NL),256,0,stream>>>(Wv, WqkvT, QL, 1024);
  wtransT<<<dim3(256,NL),256,0,stream>>>(Wo, WoT, OL, 0);
  wtransT<<<dim3(256,NL),256,0,stream>>>(Wf, WfT, OL, 0);
  bfuse<<<24,256,0,stream>>>(bq, bk, bv, bqkv);
  hinit<<<256,256,0,stream>>>(x, h0);
  gemm256<<<dim3(4,6),512,131072,stream>>>(h0, WqkvT, bqkv, q0, k0, v0, -1);

  for (int cb=0; cb<SS; cb+=RC){
    int t128 = 0, t256 = 0;
    for (int r2=0;r2<RC;r2++){ t128 += (cb+r2)/16 + 1; t256 += (cb+r2)/32 + 1; }

    // layer 0
    attn<<<dim3(RC*64),256,0,stream>>>(q0, k0, v0, q, cb, 1);
    gemm_ln<1><<<dim3(t128),512,81920,stream>>>(q, WoT, bo, h0, (size_t)1023, g1, b1, h, out, 0, cb);
    gemm_ln<2><<<dim3(t128),512,81920,stream>>>(h, WfT, bfb, h, NOMASK, g2, b2, h, out, 0, cb);

    for (int l=1;l<NL;l++){
      gemm256<<<dim3(t256,6),512,131072,stream>>>(h, WqkvT+(size_t)l*QL, bqkv+l*QKVW, q, k, v, cb);
      attn<<<dim3(RC*64),256,0,stream>>>(q, k, v, q, cb, 0);
      gemm_ln<1><<<dim3(t128),512,81920,stream>>>(q, WoT+(size_t)l*OL, bo+l*EE, h, NOMASK,
                                                  g1+l*EE, b1+l*EE, h, out, 0, cb);
      gemm_ln<2><<<dim3(t128),512,81920,stream>>>(h, WfT+(size_t)l*OL, bfb+l*EE, h, NOMASK,
                                                  g2+l*EE, b2+l*EE, h, out, (l==NL-1) ? 1 : 0, cb);
    }
  }
}

// Round 8
// 3114.052 us; speedup vs baseline: 1.0135x; 1.0135x over previous
//
#include <hip/hip_runtime.h>
#include <stdint.h>

typedef unsigned short u16;
typedef __attribute__((ext_vector_type(8))) short bf16x8;
typedef __attribute__((ext_vector_type(4))) float f32x4;

#define EE 512
#define NH 8
#define HDm 64
#define SS 128
#define NB 8
#define NL 4
#define QKVW 1536

__device__ __forceinline__ float bf2f(u16 v){ union{uint32_t u; float f;} c; c.u=((uint32_t)v)<<16; return c.f; }
__device__ __forceinline__ u16 f2bf(float f){ union{float f; uint32_t u;} c; c.f=f; uint32_t u=c.u; return (u16)((u + 0x7FFFu + ((u>>16)&1u))>>16); }

__device__ __forceinline__ f32x4 mfma16(bf16x8 a, bf16x8 b, f32x4 c){
  return __builtin_amdgcn_mfma_f32_16x16x32_bf16(a,b,c,0,0,0);
}

__device__ __forceinline__ void gload16(const u16* g, u16* l){
  auto gp = reinterpret_cast<const __attribute__((address_space(1))) uint32_t*>(reinterpret_cast<uintptr_t>(g));
  auto lp = reinterpret_cast<__attribute__((address_space(3))) uint32_t*>(reinterpret_cast<uintptr_t>(l));
  __builtin_amdgcn_global_load_lds(gp, lp, 16, 0, 0);
}

#define ABAR() asm volatile("s_barrier" ::: "memory")
#define SB0()  __builtin_amdgcn_sched_barrier(0)

// map blockIdx -> (local run r, unit u); units-per-run = ((cb+r)/16 + 1) * U
__device__ __forceinline__ void run_map(int bid, int cb, int U, int& r, int& u){
  int rr = 0;
  for (;;){
    int g = (cb + rr) >> 4;
    int gend = ((g + 1) << 4) - cb;
    int upr = (g + 1) * U;
    int span = (gend - rr) * upr;
    if (bid < span){ r = rr + bid / upr; u = bid % upr; return; }
    bid -= span; rr = gend;
  }
}

// coalesced transpose + optional input-side scale:
// dst[l*dstL + (dstOff+o)*512 + i] = bf16(W[l][i][o] * s_i), s per smode
__global__ __launch_bounds__(256) void wtransT(const float* __restrict__ W, u16* __restrict__ dst,
                                               int dstL, int dstOff, const float* __restrict__ sv, int smode){
  __shared__ float tl[32][33];
  int l = blockIdx.y;
  int tile = blockIdx.x;
  int ot = tile & 15, it = tile >> 4;
  int t = threadIdx.x;
  int c = t & 31, r = t >> 5;
  #pragma unroll
  for (int k=0;k<4;k++){
    int ri = it*32 + r + k*8;
    tl[c][r + k*8] = W[(size_t)l*262144 + (size_t)ri*512 + ot*32 + c];
  }
  __syncthreads();
  float sc = 1.f;
  if (smode == 1) sc = sv[l*512 + it*32 + c];
  else if (smode == 2) sc = (l == 0) ? 1.f : sv[(l-1)*512 + it*32 + c];
  #pragma unroll
  for (int k=0;k<4;k++){
    int ro = ot*32 + r + k*8;
    dst[(size_t)l*dstL + (size_t)(dstOff + ro)*512 + it*32 + c] = f2bf(tl[r + k*8][c] * sc);
  }
}

__global__ __launch_bounds__(256) void bfuse(const float* __restrict__ bq, const float* __restrict__ bk,
                                             const float* __restrict__ bv, float* __restrict__ bqkv){
  int i = blockIdx.x*256 + threadIdx.x;         // L*1536
  int l = i / QKVW, n = i % QKVW;
  const float* b = (n < 512) ? bq : ((n < 1024) ? bk : bv);
  bqkv[i] = b[l*EE + (n & 511)];
}

// per-column {Gw, Bw}: Gw = sum_i bf16scaledW'T[n][i] (exact cancellation vs MFMA),
// Bw = sum_i b[i] * W_f32[i][n]
__global__ __launch_bounds__(256) void gbcomp(const u16* __restrict__ WT, long wtStrideL, int wtOff,
                                              const float* __restrict__ Wf, const float* __restrict__ bvv,
                                              int lw0, int lg0, int Lcount,
                                              float2* __restrict__ outGB, int outStrideL, int outOff){
  int cidx = blockIdx.x*4 + (threadIdx.x>>6);
  if (cidx >= Lcount*512) return;
  int idx = cidx>>9, n = cidx&511;
  int lane = threadIdx.x & 63;
  const u16* wt = WT + (size_t)(lw0+idx)*wtStrideL + ((size_t)(wtOff+n))*512 + lane*8;
  bf16x8 wv = *(const bf16x8*)wt;
  const float* wsrc = Wf + (size_t)(lw0+idx)*262144 + ((size_t)(lane*8))*512 + n;
  const float* bp = bvv + (lg0+idx)*512 + lane*8;
  float gs = 0.f, bs = 0.f;
  #pragma unroll
  for (int j=0;j<8;j++){
    gs += bf2f(((const u16*)&wv)[j]);
    bs += bp[j]*wsrc[(size_t)j*512];
  }
  #pragma unroll
  for (int o=1;o<64;o<<=1){ gs += __shfl_xor(gs,o); bs += __shfl_xor(bs,o); }
  if (lane == 0) outGB[idx*outStrideL + outOff + n] = make_float2(gs, bs);
}

// h0[p][b][e] = bf16(x[b][p][e])
__global__ __launch_bounds__(256) void hinit(const float* __restrict__ x, u16* __restrict__ h0){
  int i = (blockIdx.x*256 + threadIdx.x)*8;
  int e = i & 511;
  int pb = i >> 9;
  int b = pb & 7, pp = pb >> 3;
  const float* xp = x + (((size_t)b*SS + pp)<<9) + e;
  union{ bf16x8 v; u16 u[8]; } r;
  #pragma unroll
  for (int j=0;j<8;j++) r.u[j] = f2bf(xp[j]);
  *(bf16x8*)(h0 + i) = r.v;
}

// ===== R4-proven core: 128x128 tile, BK=32, 4 waves, 2-slot dbuf, vmcnt(4) =====
// EPI 0: LN-absorbed input, +bias, split q/k/v planes (QKV l>=1)
// EPI 1: plain input, +bias+res; RESMODE 0: res = resb[(row&mask)] plain; 1: res = LN(resb,statsR,resG,resB)
// EPI 2: LN-absorbed input, relu(+bias), + res = LN(resb,statsA,resG,resB)   (FF)
// EPI 3: plain input, +bias, split planes (QKV layer 0)
// EPI 1,2 also write per-row partial {sum, sumsq} stats to statsOut[row*8 + y*2 + wn]
template<int EPI, int RESMODE>
__global__ __launch_bounds__(256) void gemm_bt(const u16* A, const u16* Bt,
                                               const float* __restrict__ bias,
                                               const float2* __restrict__ GB,
                                               const float2* statsA,
                                               const u16* resb,
                                               const float2* statsR,
                                               const float* __restrict__ resG, const float* __restrict__ resB,
                                               size_t res_mask,
                                               u16* o0, u16* o1, u16* o2,
                                               float2* statsOut,
                                               int cb){
  __shared__ u16 As[2][128*32];
  __shared__ u16 Bs[2][128*32];
  int t = threadIdx.x;
  size_t m0;
  if (cb < 0){
    m0 = (size_t)blockIdx.x * 128;
  } else {
    int r, tile; run_map(blockIdx.x, cb, 1, r, tile);
    m0 = (size_t)r*1024 + (size_t)tile*128;
  }
  int n0 = blockIdx.y*128;
  int wid=t>>6, lane=t&63;
  int wm=wid>>1, wn=wid&1, lr=lane&15, lk=(lane>>4)*8;
  f32x4 acc[4][4] = {};
  int srow=t>>2, scol=(t&3)*8;
  const u16* gA = A + (m0+(size_t)srow)*EE + scol;
  const u16* gB = Bt + ((size_t)(n0+srow))*EE + scol;

  auto stage = [&](int kt, int slot){
    int k0 = kt*32;
    u16* lA = As[slot] + t*8;
    u16* lB = Bs[slot] + t*8;
    gload16(gA+k0, lA);
    gload16(gA+64*EE+k0, lA+2048);
    gload16(gB+k0, lB);
    gload16(gB+64*EE+k0, lB+2048);
  };

  stage(0,0); stage(1,1);

  #pragma unroll
  for (int kt=0; kt<16; kt++){
    int slot = kt & 1;
    if (kt < 15) asm volatile("s_waitcnt vmcnt(4)" ::: "memory");
    else         asm volatile("s_waitcnt vmcnt(0)" ::: "memory");
    ABAR();
    bf16x8 a[4], b[4];
    #pragma unroll
    for (int mi=0;mi<4;mi++) a[mi] = *(const bf16x8*)(As[slot] + (wm*64+mi*16+lr)*32 + lk);
    #pragma unroll
    for (int ni=0;ni<4;ni++) b[ni] = *(const bf16x8*)(Bs[slot] + (wn*64+ni*16+lr)*32 + lk);
    asm volatile("s_waitcnt lgkmcnt(0)" ::: "memory");
    SB0();
    ABAR();
    if (kt < 14) stage(kt+2, slot);
    #pragma unroll
    for (int mi=0;mi<4;mi++)
      #pragma unroll
      for (int ni=0;ni<4;ni++)
        acc[mi][ni] = mfma16(a[mi], b[ni], acc[mi][ni]);
  }

  int g4 = lane>>4;
  // per-row LN stats (for absorbed input and/or res recompute)
  float mu_[4][4] = {}, rs_[4][4] = {};
  if (EPI==0 || EPI==2 || (EPI==1 && RESMODE==1)){
    const float2* stp = (EPI==1) ? statsR : statsA;
    #pragma unroll
    for (int mi=0;mi<4;mi++){
      #pragma unroll
      for (int j=0;j<4;j++){
        size_t row = m0 + (size_t)(wm*64 + mi*16 + g4*4 + j);
        float s=0.f, qq=0.f;
        #pragma unroll
        for (int k2=0;k2<8;k2++){ float2 e = stp[row*8 + k2]; s += e.x; qq += e.y; }
        float mu = s*(1.f/512.f);
        float var = qq*(1.f/512.f) - mu*mu;
        mu_[mi][j] = mu;
        rs_[mi][j] = rsqrtf(var + 1e-5f);
      }
    }
  }
  f32x4 psum[4] = {}, psq[4] = {};
  u16* outp; int nb;
  if (EPI==0 || EPI==3){ int sel = n0 >> 9; outp = sel==0 ? o0 : (sel==1 ? o1 : o2); nb = n0 & 511; }
  else                 { outp = o0; nb = n0; }
  #pragma unroll
  for (int ni=0;ni<4;ni++){
    int coln = wn*64 + ni*16 + lr;
    int gcol = n0 + coln;
    int col  = nb + coln;
    float bv = bias[gcol];
    float gw = 0.f, bw = 0.f, rg = 0.f, rb2 = 0.f;
    if (EPI==0 || EPI==2){ float2 gbv = GB[(EPI==0) ? gcol : col]; gw = gbv.x; bw = gbv.y; }
    if ((EPI==1 && RESMODE==1) || EPI==2){ rg = resG[col]; rb2 = resB[col]; }
    #pragma unroll
    for (int mi=0;mi<4;mi++){
      #pragma unroll
      for (int j=0;j<4;j++){
        size_t row = m0 + (size_t)(wm*64 + mi*16 + g4*4 + j);
        float sacc = acc[mi][ni][j];
        float v;
        if (EPI==3){
          v = sacc + bv;
        } else if (EPI==0){
          float mu = mu_[mi][j], rs = rs_[mi][j];
          v = rs*sacc - mu*rs*gw + bw + bv;
        } else if (EPI==1){
          float rv;
          if (RESMODE==0) rv = bf2f(resb[(row & res_mask)*EE + col]);
          else {
            float mu = mu_[mi][j], rs = rs_[mi][j];
            rv = (bf2f(resb[row*EE + col]) - mu)*rs*rg + rb2;
          }
          v = sacc + bv + rv;
        } else { // EPI==2
          float mu = mu_[mi][j], rs = rs_[mi][j];
          float u = rs*sacc - mu*rs*gw + bw + bv;
          u = fmaxf(u, 0.f);
          float rv = (bf2f(resb[row*EE + col]) - mu)*rs*rg + rb2;
          v = u + rv;
        }
        outp[row*EE + col] = f2bf(v);
        if (EPI==1 || EPI==2){ psum[mi][j] += v; psq[mi][j] += v*v; }
      }
    }
  }
  if (EPI==1 || EPI==2){
    #pragma unroll
    for (int o=1;o<16;o<<=1){
      #pragma unroll
      for (int mi=0;mi<4;mi++)
        #pragma unroll
        for (int j=0;j<4;j++){
          psum[mi][j] += __shfl_xor(psum[mi][j], o);
          psq[mi][j]  += __shfl_xor(psq[mi][j], o);
        }
    }
    if (lr == 0){
      int slot = blockIdx.y*2 + wn;
      #pragma unroll
      for (int mi=0;mi<4;mi++)
        #pragma unroll
        for (int j=0;j<4;j++){
          size_t row = m0 + (size_t)(wm*64 + mi*16 + g4*4 + j);
          statsOut[row*8 + slot] = make_float2(psum[mi][j], psq[mi][j]);
        }
    }
  }
}

// one block per (run, batch, head); 512-wide planes; O written into q plane
__global__ __launch_bounds__(256) void attn(const u16* __restrict__ Q, const u16* __restrict__ K,
                                            const u16* __restrict__ V, u16* __restrict__ Oq,
                                            int cb, int shared_qkv){
  __shared__ u16 Ks[128*72];
  __shared__ u16 Vt[64*136];
  __shared__ u16 Ps[4][16*136];
  int t = threadIdx.x;
  int idx = blockIdx.x;
  int hh = idx & 7, b = (idx>>3)&7, r = idx>>6;
  int m_run = cb + r;
  const size_t RS = (size_t)SS*NB*EE;
  size_t rbase = shared_qkv ? 0 : (size_t)r*RS;
  size_t hb = (size_t)b*EE + hh*HDm;
  size_t obase = (size_t)r*RS + hb;
  int nkc = m_run/32 + 1;
  int nkt = nkc*2;
  int nqt = m_run/16 + 1;
  int nkr = nkt*16;
  for (int i=t; i<nkr*8; i+=256){
    int row=i>>3, c=(i&7)*8;
    *(uint4*)(Ks + row*72 + c) = *(const uint4*)(K + rbase + (size_t)row*NB*EE + hb + c);
  }
  for (int i=t; i<nkr*8; i+=256){
    int row=i>>3, c=(i&7)*8;
    uint4 raw = *(const uint4*)(V + rbase + (size_t)row*NB*EE + hb + c);
    const u16* pv = (const u16*)&raw;
    #pragma unroll
    for (int j=0;j<8;j++) Vt[(c+j)*136 + row] = pv[j];
  }
  __syncthreads();
  int wid=t>>6, lane=t&63, lr=lane&15, g=lane>>4, lk=(lane>>4)*8;
  u16* Pw = Ps[wid];
  for (int iq=0; iq<2; iq++){
    int qt = wid*2 + iq;
    if (qt >= nqt) continue;
    const u16* qrow = Q + rbase + (size_t)(qt*16+lr)*NB*EE + hb;
    bf16x8 qa0 = *(const bf16x8*)(qrow + lk);
    bf16x8 qa1 = *(const bf16x8*)(qrow + 32 + lk);
    f32x4 sc[8];
    #pragma unroll
    for (int kt=0;kt<8;kt++){
      if (kt < nkt){
        f32x4 c = {};
        bf16x8 kb0 = *(const bf16x8*)(Ks + (kt*16+lr)*72 + lk);
        bf16x8 kb1 = *(const bf16x8*)(Ks + (kt*16+lr)*72 + 32 + lk);
        c = mfma16(qa0, kb0, c);
        c = mfma16(qa1, kb1, c);
        int key = kt*16 + lr;
        #pragma unroll
        for (int i2=0;i2<4;i2++)
          sc[kt][i2] = (key <= m_run) ? c[i2]*0.125f : -1e9f;
      }
    }
    #pragma unroll
    for (int i2=0;i2<4;i2++){
      float v = -3.0e38f;
      #pragma unroll
      for (int kt=0;kt<8;kt++) if (kt<nkt) v = fmaxf(v, sc[kt][i2]);
      v = fmaxf(v, __shfl_xor(v,1));
      v = fmaxf(v, __shfl_xor(v,2));
      v = fmaxf(v, __shfl_xor(v,4));
      v = fmaxf(v, __shfl_xor(v,8));
      float s = 0.f;
      #pragma unroll
      for (int kt=0;kt<8;kt++) if (kt<nkt){ float e2=__expf(sc[kt][i2]-v); sc[kt][i2]=e2; s+=e2; }
      s += __shfl_xor(s,1); s += __shfl_xor(s,2); s += __shfl_xor(s,4); s += __shfl_xor(s,8);
      float inv = 1.f/s;
      #pragma unroll
      for (int kt=0;kt<8;kt++) if (kt<nkt) sc[kt][i2] *= inv;
    }
    #pragma unroll
    for (int kt=0;kt<8;kt++) if (kt<nkt){
      #pragma unroll
      for (int i2=0;i2<4;i2++)
        Pw[(g*4+i2)*136 + kt*16 + lr] = f2bf(sc[kt][i2]);
    }
    f32x4 oa[4] = {};
    #pragma unroll
    for (int kc=0;kc<4;kc++) if (kc<nkc){
      bf16x8 pa = *(const bf16x8*)(Pw + lr*136 + kc*32 + lk);
      #pragma unroll
      for (int dt=0;dt<4;dt++){
        bf16x8 vb = *(const bf16x8*)(Vt + (dt*16+lr)*136 + kc*32 + lk);
        oa[dt] = mfma16(pa, vb, oa[dt]);
      }
    }
    #pragma unroll
    for (int dt=0;dt<4;dt++){
      #pragma unroll
      for (int j=0;j<4;j++){
        size_t prow = (size_t)(qt*16 + g*4 + j);
        Oq[obase + prow*NB*EE + dt*16 + lr] = f2bf(oa[dt][j]);
      }
    }
  }
}

// final: out[b][m][e] = LN(hr2[row m], stats2) with g/b of LN2 layer 3, f32 output
__global__ __launch_bounds__(256) void extractLN(const u16* __restrict__ hr2, const float2* __restrict__ stats2,
                                                 const float* __restrict__ g, const float* __restrict__ b,
                                                 float* __restrict__ out, int cb){
  int r = blockIdx.x;
  int t = threadIdx.x;
  int m = cb + r;
  #pragma unroll
  for (int it=0; it<2; it++){
    int chunk = it*256 + t;          // 0..511
    int b3 = chunk >> 6;
    int e0 = (chunk & 63)*8;
    size_t row = ((size_t)r*SS + m)*NB + b3;
    float s=0.f, qq=0.f;
    #pragma unroll
    for (int k2=0;k2<8;k2++){ float2 e = stats2[row*8 + k2]; s += e.x; qq += e.y; }
    float mu = s*(1.f/512.f);
    float var = qq*(1.f/512.f) - mu*mu;
    float rs = rsqrtf(var + 1e-5f);
    bf16x8 hv = *(const bf16x8*)(hr2 + row*EE + e0);
    #pragma unroll
    for (int j2=0;j2<8;j2++){
      float v = (bf2f(((const u16*)&hv)[j2]) - mu)*rs*g[e0+j2] + b[e0+j2];
      out[((size_t)b3*SS + m)*EE + e0 + j2] = v;
    }
  }
}

extern "C" void kernel_launch(void* const* d_in, const int* in_sizes, int n_in,
                              void* d_out, int out_size, void* d_ws, size_t ws_size,
                              hipStream_t stream){
  const float* x   = (const float*)d_in[0];
  const float* Wq  = (const float*)d_in[1];
  const float* bq  = (const float*)d_in[2];
  const float* Wk  = (const float*)d_in[3];
  const float* bk  = (const float*)d_in[4];
  const float* Wv  = (const float*)d_in[5];
  const float* bv  = (const float*)d_in[6];
  const float* Wo  = (const float*)d_in[7];
  const float* bo  = (const float*)d_in[8];
  const float* Wf  = (const float*)d_in[9];
  const float* bfb = (const float*)d_in[10];
  const float* g1  = (const float*)d_in[11];
  const float* b1  = (const float*)d_in[12];
  const float* g2  = (const float*)d_in[13];
  const float* b2  = (const float*)d_in[14];
  float* out = (float*)d_out;

  uint8_t* p = (uint8_t*)d_ws;
  u16* WqkvT  = (u16*)p; p += (size_t)NL*QKVW*EE*2;     // 6 MB
  u16* WoT    = (u16*)p; p += (size_t)NL*EE*EE*2;       // 2 MB
  u16* WfT    = (u16*)p; p += (size_t)NL*EE*EE*2;       // 2 MB
  float* bqkv = (float*)p; p += (size_t)NL*QKVW*4;      // 24 KB
  float2* GBqkv = (float2*)p; p += (size_t)3*QKVW*8;    // 36 KB (weight layers 1..3)
  float2* GBf   = (float2*)p; p += (size_t)NL*EE*8;     // 16 KB
  u16* h0 = (u16*)p; p += (size_t)SS*NB*EE*2;           // 1 MB
  u16* q0 = (u16*)p; p += (size_t)SS*NB*EE*2;
  u16* k0 = (u16*)p; p += (size_t)SS*NB*EE*2;
  u16* v0 = (u16*)p; p += (size_t)SS*NB*EE*2;
  size_t used = (size_t)(p - (uint8_t*)d_ws);

  int RC = 128;
  const size_t PER_RUN = (size_t)SS*NB*EE*2*5 + (size_t)SS*NB*8*8*2;  // hr1,hr2,q,k,v + 2 stats
  while (RC > 1 && used + (size_t)RC*PER_RUN > ws_size) RC >>= 1;

  const size_t BUF = (size_t)RC*SS*NB*EE*2;
  u16* hr1 = (u16*)p; p += BUF;
  u16* hr2 = (u16*)p; p += BUF;
  u16* q   = (u16*)p; p += BUF;
  u16* k   = (u16*)p; p += BUF;
  u16* v   = (u16*)p; p += BUF;
  float2* stats1 = (float2*)p; p += (size_t)RC*SS*NB*8*8;
  float2* stats2 = (float2*)p; p += (size_t)RC*SS*NB*8*8;

  const size_t NOMASK = ~(size_t)0;
  const int QL = QKVW*EE;
  const int OL = EE*EE;

  // weights: QKV layers 1..3 pre-scaled by g2[l-1]; Wf scaled by g1[l]; Wo plain
  wtransT<<<dim3(256,NL),256,0,stream>>>(Wq, WqkvT, QL, 0,    g2, 2);
  wtransT<<<dim3(256,NL),256,0,stream>>>(Wk, WqkvT, QL, 512,  g2, 2);
  wtransT<<<dim3(256,NL),256,0,stream>>>(Wv, WqkvT, QL, 1024, g2, 2);
  wtransT<<<dim3(256,NL),256,0,stream>>>(Wo, WoT, OL, 0, nullptr, 0);
  wtransT<<<dim3(256,NL),256,0,stream>>>(Wf, WfT, OL, 0, g1, 1);
  bfuse<<<24,256,0,stream>>>(bq, bk, bv, bqkv);
  gbcomp<<<384,256,0,stream>>>(WqkvT, QL, 0,    Wq, b2, 1, 0, 3, GBqkv, QKVW, 0);
  gbcomp<<<384,256,0,stream>>>(WqkvT, QL, 512,  Wk, b2, 1, 0, 3, GBqkv, QKVW, 512);
  gbcomp<<<384,256,0,stream>>>(WqkvT, QL, 1024, Wv, b2, 1, 0, 3, GBqkv, QKVW, 1024);
  gbcomp<<<512,256,0,stream>>>(WfT, OL, 0, Wf, b1, 0, 0, 4, GBf, EE, 0);
  hinit<<<256,256,0,stream>>>(x, h0);
  // layer-0 QKV once for all runs (plain, shared)
  gemm_bt<3,0><<<dim3(8,12),256,0,stream>>>(h0, WqkvT, bqkv, nullptr, nullptr, nullptr, nullptr,
                                            nullptr, nullptr, 0, q0, k0, v0, nullptr, -1);

  for (int cb=0; cb<SS; cb+=RC){
    int t128 = 0;
    for (int r2=0;r2<RC;r2++) t128 += (cb+r2)/16 + 1;

    for (int l=0;l<NL;l++){
      // attention
      if (l == 0) attn<<<dim3(RC*64),256,0,stream>>>(q0, k0, v0, q, cb, 1);
      else        attn<<<dim3(RC*64),256,0,stream>>>(q, k, v, q, cb, 0);

      // Wo: plain input, res = h_{l-1}; writes raw v1 + stats1
      if (l == 0)
        gemm_bt<1,0><<<dim3(t128,4),256,0,stream>>>(q, WoT, bo, nullptr, nullptr,
                                                    h0, nullptr, nullptr, nullptr, (size_t)1023,
                                                    hr1, nullptr, nullptr, stats1, cb);
      else
        gemm_bt<1,1><<<dim3(t128,4),256,0,stream>>>(q, WoT+(size_t)l*OL, bo+l*EE, nullptr, nullptr,
                                                    hr2, stats2, g2+(l-1)*EE, b2+(l-1)*EE, NOMASK,
                                                    hr1, nullptr, nullptr, stats1, cb);

      // FF: LN1-absorbed input (hr1,stats1), res = LN1(hr1); writes raw v2 + stats2
      gemm_bt<2,1><<<dim3(t128,4),256,0,stream>>>(hr1, WfT+(size_t)l*OL, bfb+l*EE, GBf+l*EE, stats1,
                                                  hr1, nullptr, g1+l*EE, b1+l*EE, NOMASK,
                                                  hr2, nullptr, nullptr, stats2, cb);

      // QKV for layer l+1: LN2-absorbed input (hr2,stats2)
      if (l < NL-1)
        gemm_bt<0,0><<<dim3(t128,12),256,0,stream>>>(hr2, WqkvT+(size_t)(l+1)*QL, bqkv+(l+1)*QKVW,
                                                     GBqkv+(size_t)l*QKVW, stats2,
                                                     nullptr, nullptr, nullptr, nullptr, 0,
                                                     q, k, v, nullptr, cb);
    }
    extractLN<<<dim3(RC),256,0,stream>>>(hr2, stats2, g2+(NL-1)*EE, b2+(NL-1)*EE, out, cb);
  }
}

// Round 9
// 1867.931 us; speedup vs baseline: 1.6896x; 1.6671x over previous
//
#include <hip/hip_runtime.h>
#include <stdint.h>

typedef unsigned short u16;
typedef __attribute__((ext_vector_type(8))) short bf16x8;
typedef __attribute__((ext_vector_type(4))) float f32x4;

#define EE 512
#define NH 8
#define HDm 64
#define SS 128
#define NB 8
#define NL 4
#define QKVW 1536

__device__ __forceinline__ float bf2f(u16 v){ union{uint32_t u; float f;} c; c.u=((uint32_t)v)<<16; return c.f; }
__device__ __forceinline__ u16 f2bf(float f){ union{float f; uint32_t u;} c; c.f=f; uint32_t u=c.u; return (u16)((u + 0x7FFFu + ((u>>16)&1u))>>16); }

__device__ __forceinline__ f32x4 mfma16(bf16x8 a, bf16x8 b, f32x4 c){
  return __builtin_amdgcn_mfma_f32_16x16x32_bf16(a,b,c,0,0,0);
}

__device__ __forceinline__ void gload16(const u16* g, u16* l){
  auto gp = reinterpret_cast<const __attribute__((address_space(1))) uint32_t*>(reinterpret_cast<uintptr_t>(g));
  auto lp = reinterpret_cast<__attribute__((address_space(3))) uint32_t*>(reinterpret_cast<uintptr_t>(l));
  __builtin_amdgcn_global_load_lds(gp, lp, 16, 0, 0);
}

#define ABAR() asm volatile("s_barrier" ::: "memory")
#define SB0()  __builtin_amdgcn_sched_barrier(0)

// map blockIdx -> (local run r, unit u); units-per-run = ((cb+r)/16 + 1) * U
__device__ __forceinline__ void run_map(int bid, int cb, int U, int& r, int& u){
  int rr = 0;
  for (;;){
    int g = (cb + rr) >> 4;
    int gend = ((g + 1) << 4) - cb;
    int upr = (g + 1) * U;
    int span = (gend - rr) * upr;
    if (bid < span){ r = rr + bid / upr; u = bid % upr; return; }
    bid -= span; rr = gend;
  }
}

// coalesced transpose: dst[l*dstL + (dstOff + o)*512 + i] = bf16(W[l][i][o])
__global__ __launch_bounds__(256) void wtransT(const float* __restrict__ W, u16* __restrict__ dst,
                                               int dstL, int dstOff){
  __shared__ float tl[32][33];
  int l = blockIdx.y;
  int tile = blockIdx.x;
  int ot = tile & 15, it = tile >> 4;
  int t = threadIdx.x;
  int c = t & 31, r = t >> 5;
  #pragma unroll
  for (int k=0;k<4;k++){
    int ri = it*32 + r + k*8;
    tl[c][r + k*8] = W[(size_t)l*262144 + (size_t)ri*512 + ot*32 + c];
  }
  __syncthreads();
  #pragma unroll
  for (int k=0;k<4;k++){
    int ro = ot*32 + r + k*8;
    dst[(size_t)l*dstL + (size_t)(dstOff + ro)*512 + it*32 + c] = f2bf(tl[r + k*8][c]);
  }
}

__global__ __launch_bounds__(256) void bfuse(const float* __restrict__ bq, const float* __restrict__ bk,
                                             const float* __restrict__ bv, float* __restrict__ bqkv){
  int i = blockIdx.x*256 + threadIdx.x;         // L*1536
  int l = i / QKVW, n = i % QKVW;
  const float* b = (n < 512) ? bq : ((n < 1024) ? bk : bv);
  bqkv[i] = b[l*EE + (n & 511)];
}

// h0[p][b][e] = bf16(x[b][p][e])
__global__ __launch_bounds__(256) void hinit(const float* __restrict__ x, u16* __restrict__ h0){
  int i = (blockIdx.x*256 + threadIdx.x)*8;
  int e = i & 511;
  int pb = i >> 9;
  int b = pb & 7, pp = pb >> 3;
  const float* xp = x + (((size_t)b*SS + pp)<<9) + e;
  union{ bf16x8 v; u16 u[8]; } r;
  #pragma unroll
  for (int j=0;j<8;j++) r.u[j] = f2bf(xp[j]);
  *(bf16x8*)(h0 + i) = r.v;
}

// 128x128 tile, BK=64, 4 waves, double-buffered LDS (2 x 32KB), counted vmcnt(8), raw barriers.
// T2 XOR swizzle (source-side, both-sides involution) -> conflict-free ds_read_b128.
// XCD-aware block remap (bijective when gridDim.x % 8 == 0): same A-tile's y-blocks run
// consecutively on the same XCD -> A served from that XCD's private L2.
// MODE 0: +bias, split write to o0/o1/o2 by n-block (fused QKV); 1: +bias+res; 2: relu(+bias)+res
template<int MODE>
__global__ __launch_bounds__(256) void gemm_bt(const u16* __restrict__ A, const u16* __restrict__ Bt,
                                               const float* __restrict__ bias, const u16* __restrict__ res,
                                               u16* __restrict__ o0, u16* __restrict__ o1, u16* __restrict__ o2,
                                               int cb, size_t res_mask){
  __shared__ u16 As[2][128*64];
  __shared__ u16 Bs[2][128*64];
  int t = threadIdx.x;
  // ---- XCD-aware remap of (tile, yb) ----
  int T = gridDim.x, NY = gridDim.y;
  int tile_idx, yb;
  if ((T & 7) == 0){
    int hw = blockIdx.y * T + blockIdx.x;   // hw dispatch order (x fastest)
    int xcd = hw & 7, u = hw >> 3;
    yb = u % NY;
    tile_idx = (u / NY) * 8 + xcd;
  } else { tile_idx = blockIdx.x; yb = blockIdx.y; }
  size_t m0;
  if (cb < 0){
    m0 = (size_t)tile_idx * 128;
  } else {
    int r, tile; run_map(tile_idx, cb, 1, r, tile);
    m0 = (size_t)r*1024 + (size_t)tile*128;
  }
  int n0 = yb*128;
  int wid=t>>6, lane=t&63;
  int wm=wid>>1, wn=wid&1, lr=lane&15, lq=lane>>4;
  f32x4 acc[4][4] = {};
  int srow = t>>3;                        // staging row 0..31 (+j*32)
  int cg = (t&7) ^ (srow&7);              // source-side swizzled chunk
  const u16* gA = A + (m0+(size_t)srow)*EE + cg*8;
  const u16* gB = Bt + ((size_t)(n0+srow))*EE + cg*8;

  auto stage = [&](int kt, int slot){
    int k0 = kt*64;
    u16* lA = As[slot] + t*8;
    u16* lB = Bs[slot] + t*8;
    #pragma unroll
    for (int j=0;j<4;j++){
      gload16(gA + (size_t)j*32*EE + k0, lA + j*2048);
      gload16(gB + (size_t)j*32*EE + k0, lB + j*2048);
    }
  };

  stage(0,0); stage(1,1);    // 16 per-lane loads in flight

  #pragma unroll
  for (int kt=0; kt<8; kt++){
    int slot = kt & 1;
    if (kt < 7) asm volatile("s_waitcnt vmcnt(8)" ::: "memory");
    else        asm volatile("s_waitcnt vmcnt(0)" ::: "memory");
    ABAR();                                  // slot data landed for all waves
    bf16x8 a[4][2], b[4][2];
    #pragma unroll
    for (int mi=0;mi<4;mi++){
      int row = wm*64 + mi*16 + lr;
      #pragma unroll
      for (int kk=0;kk<2;kk++){
        int c = (kk*4 + lq) ^ (row&7);
        a[mi][kk] = *(const bf16x8*)(As[slot] + row*64 + c*8);
      }
    }
    #pragma unroll
    for (int ni=0;ni<4;ni++){
      int row = wn*64 + ni*16 + lr;
      #pragma unroll
      for (int kk=0;kk<2;kk++){
        int c = (kk*4 + lq) ^ (row&7);
        b[ni][kk] = *(const bf16x8*)(Bs[slot] + row*64 + c*8);
      }
    }
    asm volatile("s_waitcnt lgkmcnt(0)" ::: "memory");
    SB0();
    ABAR();                                  // all reads done, slot reusable
    if (kt < 6) stage(kt+2, slot);
    #pragma unroll
    for (int mi=0;mi<4;mi++)
      #pragma unroll
      for (int ni=0;ni<4;ni++){
        acc[mi][ni] = mfma16(a[mi][0], b[ni][0], acc[mi][ni]);
        acc[mi][ni] = mfma16(a[mi][1], b[ni][1], acc[mi][ni]);
      }
  }

  int g4 = lane>>4;
  u16* outp;
  int nb;
  if (MODE==0){ int sel = n0 >> 9; outp = sel==0 ? o0 : (sel==1 ? o1 : o2); nb = n0 & 511; }
  else        { outp = o0; nb = n0; }
  #pragma unroll
  for (int ni=0;ni<4;ni++){
    int coln = wn*64 + ni*16 + lr;
    float bv = bias[n0 + coln];
    int col = nb + coln;
    #pragma unroll
    for (int mi=0;mi<4;mi++){
      #pragma unroll
      for (int j=0;j<4;j++){
        size_t row = m0 + (size_t)(wm*64 + mi*16 + g4*4 + j);
        float v = acc[mi][ni][j] + bv;
        if (MODE==2) v = fmaxf(v, 0.f);
        if (MODE>=1) v += bf2f(res[(row & res_mask)*EE + col]);
        outp[row*EE + col] = f2bf(v);
      }
    }
  }
}

// one block per (run, batch, head); layout [r][p][b][e] (512-wide planes);
// reads Q/K/V (rbase=0 if shared), writes O in-place into Oq (per-run q plane)
__global__ __launch_bounds__(256) void attn(const u16* __restrict__ Q, const u16* __restrict__ K,
                                            const u16* __restrict__ V, u16* __restrict__ Oq,
                                            int cb, int shared_qkv){
  __shared__ u16 Ks[128*72];
  __shared__ u16 Vt[64*136];
  __shared__ u16 Ps[4][16*136];
  int t = threadIdx.x;
  int idx = blockIdx.x;
  int hh = idx & 7, b = (idx>>3)&7, r = idx>>6;
  int m_run = cb + r;
  const size_t RS = (size_t)SS*NB*EE;
  size_t rbase = shared_qkv ? 0 : (size_t)r*RS;
  size_t hb = (size_t)b*EE + hh*HDm;
  size_t obase = (size_t)r*RS + hb;
  int nkc = m_run/32 + 1;
  int nkt = nkc*2;
  int nqt = m_run/16 + 1;
  int nkr = nkt*16;
  for (int i=t; i<nkr*8; i+=256){
    int row=i>>3, c=(i&7)*8;
    *(uint4*)(Ks + row*72 + c) = *(const uint4*)(K + rbase + (size_t)row*NB*EE + hb + c);
  }
  for (int i=t; i<nkr*8; i+=256){
    int row=i>>3, c=(i&7)*8;
    uint4 raw = *(const uint4*)(V + rbase + (size_t)row*NB*EE + hb + c);
    const u16* pv = (const u16*)&raw;
    #pragma unroll
    for (int j=0;j<8;j++) Vt[(c+j)*136 + row] = pv[j];
  }
  __syncthreads();
  int wid=t>>6, lane=t&63, lr=lane&15, g=lane>>4, lk=(lane>>4)*8;
  u16* Pw = Ps[wid];
  for (int iq=0; iq<2; iq++){
    int qt = wid*2 + iq;
    if (qt >= nqt) continue;
    const u16* qrow = Q + rbase + (size_t)(qt*16+lr)*NB*EE + hb;
    bf16x8 qa0 = *(const bf16x8*)(qrow + lk);
    bf16x8 qa1 = *(const bf16x8*)(qrow + 32 + lk);
    f32x4 sc[8];
    #pragma unroll
    for (int kt=0;kt<8;kt++){
      if (kt < nkt){
        f32x4 c = {};
        bf16x8 kb0 = *(const bf16x8*)(Ks + (kt*16+lr)*72 + lk);
        bf16x8 kb1 = *(const bf16x8*)(Ks + (kt*16+lr)*72 + 32 + lk);
        c = mfma16(qa0, kb0, c);
        c = mfma16(qa1, kb1, c);
        int key = kt*16 + lr;
        #pragma unroll
        for (int i2=0;i2<4;i2++)
          sc[kt][i2] = (key <= m_run) ? c[i2]*0.125f : -1e9f;
      }
    }
    #pragma unroll
    for (int i2=0;i2<4;i2++){
      float v = -3.0e38f;
      #pragma unroll
      for (int kt=0;kt<8;kt++) if (kt<nkt) v = fmaxf(v, sc[kt][i2]);
      v = fmaxf(v, __shfl_xor(v,1));
      v = fmaxf(v, __shfl_xor(v,2));
      v = fmaxf(v, __shfl_xor(v,4));
      v = fmaxf(v, __shfl_xor(v,8));
      float s = 0.f;
      #pragma unroll
      for (int kt=0;kt<8;kt++) if (kt<nkt){ float e2=__expf(sc[kt][i2]-v); sc[kt][i2]=e2; s+=e2; }
      s += __shfl_xor(s,1); s += __shfl_xor(s,2); s += __shfl_xor(s,4); s += __shfl_xor(s,8);
      float inv = 1.f/s;
      #pragma unroll
      for (int kt=0;kt<8;kt++) if (kt<nkt) sc[kt][i2] *= inv;
    }
    #pragma unroll
    for (int kt=0;kt<8;kt++) if (kt<nkt){
      #pragma unroll
      for (int i2=0;i2<4;i2++)
        Pw[(g*4+i2)*136 + kt*16 + lr] = f2bf(sc[kt][i2]);
    }
    f32x4 oa[4] = {};
    #pragma unroll
    for (int kc=0;kc<4;kc++) if (kc<nkc){
      bf16x8 pa = *(const bf16x8*)(Pw + lr*136 + kc*32 + lk);
      #pragma unroll
      for (int dt=0;dt<4;dt++){
        bf16x8 vb = *(const bf16x8*)(Vt + (dt*16+lr)*136 + kc*32 + lk);
        oa[dt] = mfma16(pa, vb, oa[dt]);
      }
    }
    #pragma unroll
    for (int dt=0;dt<4;dt++){
      #pragma unroll
      for (int j=0;j<4;j++){
        size_t prow = (size_t)(qt*16 + g*4 + j);
        Oq[obase + prow*NB*EE + dt*16 + lr] = f2bf(oa[dt][j]);
      }
    }
  }
}

// LN over E=512; one wave per row; run-mapped (U=8 -> 16 rows per unit, 4 per loop step)
__global__ __launch_bounds__(256) void lnorm(const u16* __restrict__ in, const float* __restrict__ gg,
                                             const float* __restrict__ bb, u16* __restrict__ outp, int cb){
  int r, u; run_map(blockIdx.x, cb, 8, r, u);
  int lane = threadIdx.x & 63;
  float gv[8], bv2[8];
  #pragma unroll
  for (int j=0;j<8;j++){ gv[j] = gg[lane*8+j]; bv2[j] = bb[lane*8+j]; }
  #pragma unroll
  for (int it=0; it<4; it++){
    size_t row = (size_t)r*1024 + (size_t)u*16 + it*4 + (threadIdx.x>>6);
    const u16* p = in + row*EE + lane*8;
    union{ bf16x8 v; u16 u[8]; } d; d.v = *(const bf16x8*)p;
    float f[8]; float s=0.f;
    #pragma unroll
    for (int j=0;j<8;j++){ f[j]=bf2f(d.u[j]); s+=f[j]; }
    #pragma unroll
    for (int o=1;o<64;o<<=1) s += __shfl_xor(s,o);
    float mu = s*(1.f/512.f);
    float s2=0.f;
    #pragma unroll
    for (int j=0;j<8;j++){ float tt=f[j]-mu; s2+=tt*tt; }
    #pragma unroll
    for (int o=1;o<64;o<<=1) s2 += __shfl_xor(s2,o);
    float rstd = rsqrtf(s2*(1.f/512.f)+1e-5f);
    union{ bf16x8 v; u16 u[8]; } rr;
    #pragma unroll
    for (int j=0;j<8;j++) rr.u[j] = f2bf((f[j]-mu)*rstd*gv[j] + bv2[j]);
    *(bf16x8*)(outp + row*EE + lane*8) = rr.v;
  }
}

// out[b][m][e] = f32(h[r][p=m][b][e]), m = cb + r
__global__ __launch_bounds__(256) void extract(const u16* __restrict__ h, float* __restrict__ out, int cb){
  int i = blockIdx.x*256 + threadIdx.x;
  int e = i & 511;
  int b = (i >> 9) & 7;
  int r = i >> 12;
  int m = cb + r;
  out[((size_t)b*SS + m)*EE + e] = bf2f(h[(((size_t)r*SS + m)*NB + b)*EE + e]);
}

extern "C" void kernel_launch(void* const* d_in, const int* in_sizes, int n_in,
                              void* d_out, int out_size, void* d_ws, size_t ws_size,
                              hipStream_t stream){
  const float* x   = (const float*)d_in[0];
  const float* Wq  = (const float*)d_in[1];
  const float* bq  = (const float*)d_in[2];
  const float* Wk  = (const float*)d_in[3];
  const float* bk  = (const float*)d_in[4];
  const float* Wv  = (const float*)d_in[5];
  const float* bv  = (const float*)d_in[6];
  const float* Wo  = (const float*)d_in[7];
  const float* bo  = (const float*)d_in[8];
  const float* Wf  = (const float*)d_in[9];
  const float* bfb = (const float*)d_in[10];
  const float* g1  = (const float*)d_in[11];
  const float* b1  = (const float*)d_in[12];
  const float* g2  = (const float*)d_in[13];
  const float* b2  = (const float*)d_in[14];
  float* out = (float*)d_out;

  uint8_t* p = (uint8_t*)d_ws;
  u16* WqkvT = (u16*)p; p += (size_t)NL*QKVW*EE*2;   // 6 MB
  u16* WoT   = (u16*)p; p += (size_t)NL*EE*EE*2;     // 2 MB
  u16* WfT   = (u16*)p; p += (size_t)NL*EE*EE*2;     // 2 MB
  float* bqkv= (float*)p; p += (size_t)NL*QKVW*4;    // 24 KB
  u16* h0    = (u16*)p; p += (size_t)SS*NB*EE*2;     // 1 MB
  u16* q0    = (u16*)p; p += (size_t)SS*NB*EE*2;
  u16* k0    = (u16*)p; p += (size_t)SS*NB*EE*2;
  u16* v0    = (u16*)p; p += (size_t)SS*NB*EE*2;
  size_t used = (size_t)(p - (uint8_t*)d_ws);

  int RC = 128;
  const size_t PER_RUN = (size_t)SS*NB*EE*2*5;       // h,q,k,v,tmp = 5 MiB/run
  while (RC > 1 && used + (size_t)RC*PER_RUN > ws_size) RC >>= 1;

  const size_t BUF = (size_t)RC*SS*NB*EE*2;
  u16* h   = (u16*)p; p += BUF;
  u16* q   = (u16*)p; p += BUF;
  u16* k   = (u16*)p; p += BUF;
  u16* v   = (u16*)p; p += BUF;
  u16* tmp = (u16*)p; p += BUF;

  const size_t NOMASK = ~(size_t)0;
  const int QL = QKVW*EE;
  const int OL = EE*EE;

  wtransT<<<dim3(256,NL),256,0,stream>>>(Wq, WqkvT, QL, 0);
  wtransT<<<dim3(256,NL),256,0,stream>>>(Wk, WqkvT, QL, 512);
  wtransT<<<dim3(256,NL),256,0,stream>>>(Wv, WqkvT, QL, 1024);
  wtransT<<<dim3(256,NL),256,0,stream>>>(Wo, WoT, OL, 0);
  wtransT<<<dim3(256,NL),256,0,stream>>>(Wf, WfT, OL, 0);
  bfuse<<<24,256,0,stream>>>(bq, bk, bv, bqkv);
  hinit<<<256,256,0,stream>>>(x, h0);
  // layer-0 QKV once for all runs (plain tiles, 1024 rows)
  gemm_bt<0><<<dim3(8,12),256,0,stream>>>(h0, WqkvT, bqkv, nullptr, q0, k0, v0, -1, 0);

  for (int cb=0; cb<SS; cb+=RC){
    int t128 = 0;
    for (int r2=0;r2<RC;r2++) t128 += (cb+r2)/16 + 1;

    // layer 0
    attn<<<dim3(RC*64),256,0,stream>>>(q0, k0, v0, q, cb, 1);
    gemm_bt<1><<<dim3(t128,4),256,0,stream>>>(q, WoT, bo, h0, tmp, tmp, tmp, cb, (size_t)1023);
    lnorm<<<dim3(t128*8),256,0,stream>>>(tmp, g1, b1, h, cb);
    gemm_bt<2><<<dim3(t128,4),256,0,stream>>>(h, WfT, bfb, h, tmp, tmp, tmp, cb, NOMASK);
    lnorm<<<dim3(t128*8),256,0,stream>>>(tmp, g2, b2, h, cb);

    for (int l=1;l<NL;l++){
      gemm_bt<0><<<dim3(t128,12),256,0,stream>>>(h, WqkvT+(size_t)l*QL, bqkv+l*QKVW, nullptr, q, k, v, cb, 0);
      attn<<<dim3(RC*64),256,0,stream>>>(q, k, v, q, cb, 0);
      gemm_bt<1><<<dim3(t128,4),256,0,stream>>>(q, WoT+(size_t)l*OL, bo+l*EE, h, tmp, tmp, tmp, cb, NOMASK);
      lnorm<<<dim3(t128*8),256,0,stream>>>(tmp, g1+l*EE, b1+l*EE, h, cb);
      gemm_bt<2><<<dim3(t128,4),256,0,stream>>>(h, WfT+(size_t)l*OL, bfb+l*EE, h, tmp, tmp, tmp, cb, NOMASK);
      lnorm<<<dim3(t128*8),256,0,stream>>>(tmp, g2+l*EE, b2+l*EE, h, cb);
    }
    extract<<<dim3(RC*16),256,0,stream>>>(h, out, cb);
  }
}